// Round 11
// baseline (156.640 us; speedup 1.0000x reference)
//
#include <hip/hip_runtime.h>
#include <hip/hip_bf16.h>
#include <math.h>

#define H   64
#define L   6
#define TE  32
#define SEL 64
#define CD  128
#define DC  128
#define KK  16
#define BB  32
#define NN  8192
#define EPSV 1e-6f

typedef float f32x4  __attribute__((ext_vector_type(4)));
typedef short bf16x8 __attribute__((ext_vector_type(8)));
typedef short bf16x4 __attribute__((ext_vector_type(4)));

__device__ __forceinline__ float swish_f(float v) {
    return v * __builtin_amdgcn_rcpf(1.0f + __expf(-v));
}
__device__ __forceinline__ short f2bf(float f) {
    __hip_bfloat16 h = __float2bfloat16(f);
    return *reinterpret_cast<short*>(&h);
}

// Cross-lane all-reduce over lane-bits 4,5 (R9/R10-verified correct).
// R7/R8 LESSON: never hand-roll permlane in inline asm (regalloc coalescing
// + VALU wait-state hazards the compiler only fixes for its own code).
#if __has_builtin(__builtin_amdgcn_permlane16_swap) && __has_builtin(__builtin_amdgcn_permlane32_swap)
__device__ __forceinline__ float red_add64(float x) {
    auto r16 = __builtin_amdgcn_permlane16_swap(__float_as_uint(x), __float_as_uint(x), false, false);
    float s = __uint_as_float(r16[0]) + __uint_as_float(r16[1]);
    auto r32 = __builtin_amdgcn_permlane32_swap(__float_as_uint(s), __float_as_uint(s), false, false);
    return __uint_as_float(r32[0]) + __uint_as_float(r32[1]);
}
__device__ __forceinline__ float red_max64(float x) {
    auto r16 = __builtin_amdgcn_permlane16_swap(__float_as_uint(x), __float_as_uint(x), false, false);
    float s = fmaxf(__uint_as_float(r16[0]), __uint_as_float(r16[1]));
    auto r32 = __builtin_amdgcn_permlane32_swap(__float_as_uint(s), __float_as_uint(s), false, false);
    return fmaxf(__uint_as_float(r32[0]), __uint_as_float(r32[1]));
}
#else
__device__ __forceinline__ float red_add64(float x) {
    x += __shfl_xor(x, 16);
    x += __shfl_xor(x, 32);
    return x;
}
__device__ __forceinline__ float red_max64(float x) {
    x = fmaxf(x, __shfl_xor(x, 16));
    x = fmaxf(x, __shfl_xor(x, 32));
    return x;
}
#endif

// 16x16x16 bf16 MFMA: builtin spelling ...16x16x16bf16_1k; asm fallback with
// EARLY-CLOBBER dest so D never aliases A/B/C (R4's corruption).
#if __has_builtin(__builtin_amdgcn_mfma_f32_16x16x16bf16_1k)
#define MFMA16(a, b, c) __builtin_amdgcn_mfma_f32_16x16x16bf16_1k(a, b, c, 0, 0, 0)
#else
__device__ __forceinline__ f32x4 mfma16_asm(bf16x4 a, bf16x4 b, f32x4 c) {
    f32x4 d;
    asm("v_mfma_f32_16x16x16_bf16 %0, %1, %2, %3" : "=&v"(d) : "v"(a), "v"(b), "v"(c));
    return d;
}
#define MFMA16(a, b, c) mfma16_asm(a, b, c)
#endif
#define MFMA32(a, b, c) __builtin_amdgcn_mfma_f32_16x16x32_bf16(a, b, c, 0, 0, 0)

// ws layout (shorts):
//   objffrag [32][2][64][8]     = 32768
//   tabfrag  [32][6][8][64][4]  = 393216   (16x16x16 A-frag, K=16 exact)
//   whfrag   [6][4][2][64][8]   = 24576
//   wpffrag  [4][2][64][8]      = 4096
#define OFF_OBJF 0
#define OFF_TAB  32768
#define OFF_WH   425984
#define OFF_WPF  450560

// ---------------------------------------------------------------------------
// Fused setup (one dispatch): blocks 0..511 = per-(b,k) object setup
// (128 active threads + barriers hit by all 256); blocks 512..543 = weight
// A-frag setup. Saves one launch boundary vs R10's two kernels.
// ---------------------------------------------------------------------------
__global__ void setup_all(const float* __restrict__ c, const float* __restrict__ t,
                          const float* __restrict__ W_of, const float* __restrict__ b_of,
                          const float* __restrict__ W_c1, const float* __restrict__ b_c1,
                          const float* __restrict__ W_c2, const float* __restrict__ b_c2,
                          const float* __restrict__ W_ss, const float* __restrict__ b_ss,
                          const float* __restrict__ W_h,  const float* __restrict__ W_pf,
                          short* __restrict__ objffrag, short* __restrict__ tabfrag,
                          short* __restrict__ whfrag,   short* __restrict__ wpffrag) {
    if (blockIdx.x >= 512) {
        // ---- weight A-frags: A[row=16t+(lane&15)][k=32s+8*(lane>>4)+jj] ----
        const int gid = (blockIdx.x - 512) * 256 + threadIdx.x;   // 8192 threads
        for (int idx = gid; idx < 6 * 4 * 2 * 64 * 8; idx += 8192) {
            const int jj = idx & 7, lane = (idx >> 3) & 63, s = (idx >> 9) & 1,
                      tt = (idx >> 10) & 3, l = idx >> 12;
            const int g = lane >> 4, row = 16 * tt + (lane & 15), k = 32 * s + 8 * g + jj;
            whfrag[idx] = f2bf(W_h[(l * H + k) * H + row]);
        }
        for (int idx = gid; idx < 4 * 2 * 64 * 8; idx += 8192) {
            const int jj = idx & 7, lane = (idx >> 3) & 63, s = (idx >> 9) & 1, tt = idx >> 10;
            const int g = lane >> 4, row = 16 * tt + (lane & 15), k = 32 * s + 8 * g + jj;
            wpffrag[idx] = f2bf(W_pf[k * SEL + row]);
        }
        return;
    }

    // ---- per-(b,k) object setup (obj A-frag layout HW-verified R3/R6) ----
    const int bk = blockIdx.x, b = bk >> 4, k = bk & 15;
    const int tid = threadIdx.x;                        // 0..255, work on 0..127
    __shared__ float cwt[TE + DC];
    __shared__ float c1s[CD], c2s[CD];

    if (tid < 16) {
        float f   = __expf(-logf(10000.0f) * (float)tid * (1.0f / 15.0f));
        float arg = t[b] * f;
        cwt[tid]      = sinf(arg);
        cwt[tid + 16] = cosf(arg);
    }
    if (tid < 128) cwt[TE + tid] = c[(b * KK + k) * DC + tid];
    __syncthreads();

    if (tid < SEL) {   // object_features -> A-frag rows = object k, k-dim = tid
        float a = b_of[tid];
        for (int d = 0; d < TE + DC; ++d) a += cwt[d] * W_of[d * SEL + tid];
        a = swish_f(a);
        const int s = tid >> 5, g = (tid >> 3) & 3, jj = tid & 7;
        objffrag[(((b * 2 + s) * 64) + (16 * g + k)) * 8 + jj] = f2bf(a);
    }
    if (tid < 128) {
        float a = b_c1[tid];
        for (int d = 0; d < TE + DC; ++d) a += cwt[d] * W_c1[d * CD + tid];
        c1s[tid] = swish_f(a);
    }
    __syncthreads();
    if (tid < 128) {
        float a = b_c2[tid];
        for (int d = 0; d < CD; ++d) a += c1s[d] * W_c2[d * CD + tid];
        c2s[tid] = swish_f(a);
    }
    __syncthreads();

    if (tid < 128) {
        // tab[l][j=tid] = c2 @ W_ss[l,:,j] + b_ss[l,j]
        // A-frag (16x16x16): u=j>>4, row=j&15, lane=16*(k>>2)+row, jj=k&3
        const int u = tid >> 4, row = tid & 15, lane = 16 * (k >> 2) + row, jj = k & 3;
        for (int l = 0; l < L; ++l) {
            const float* W = W_ss + l * CD * (2 * H);
            float a = b_ss[l * (2 * H) + tid];
            for (int d = 0; d < CD; ++d) a += c2s[d] * W[d * (2 * H) + tid];
            tabfrag[(((b * 6 + l) * 8 + u) * 64 + lane) * 4 + jj] = f2bf(a);
        }
    }
}

// ---------------------------------------------------------------------------
// Main: 2048 blocks x 256 threads (4 waves), 2 point-tiles/wave (128 pts/
// block), ZERO barriers (hlds wave-exclusive).
// __launch_bounds__(256,4): layer-loop peak = 84 VGPR (whr32+tabr8+sf2+hb8+
// hn16+misc) + 32 AGPR (sca+macc, macc dies before sha) ~= 116-120 <= 128
// budget -> 4 blocks/CU, 16 waves/CU (50% ceiling) without spills.
// (R3's (256,4) spill was the fat 4-tile/K32 live set ~165 — different kernel.)
// Tripwire: FETCH_SIZE >15MB => spilled, revert to (256,3).
// ---------------------------------------------------------------------------
__global__ __launch_bounds__(256, 4) void main_kernel(
    const float* __restrict__ x,
    const float* __restrict__ W_emb, const float* __restrict__ b_emb,
    const float* __restrict__ b_pf,  const float* __restrict__ b_h,
    const float* __restrict__ ln_g,  const float* __restrict__ ln_b,
    const float* __restrict__ W_out, const float* __restrict__ b_out,
    const short* __restrict__ objffrag, const short* __restrict__ tabfrag,
    const short* __restrict__ whfrag,   const short* __restrict__ wpffrag,
    float* __restrict__ out) {

    __shared__ short hlds[128 * 72];        // [point][dim], stride 72 shorts

    const int tid  = threadIdx.x;
    const int wave = tid >> 6, lane = tid & 63;
    const int p = lane & 15, g = lane >> 4;
    const int b = blockIdx.x >> 6;                  // 64 blocks / batch
    const int point0 = (blockIdx.x & 63) << 7;      // 128 points / block

    bf16x8 wpfr[4][2], objr[2];
#pragma unroll
    for (int t = 0; t < 4; ++t)
#pragma unroll
        for (int s = 0; s < 2; ++s)
            wpfr[t][s] = *(const bf16x8*)&wpffrag[(((t * 2 + s) * 64) + lane) * 8];
#pragma unroll
    for (int s = 0; s < 2; ++s)
        objr[s] = *(const bf16x8*)&objffrag[(((b * 2 + s) * 64) + lane) * 8];

    bf16x4 swfrag[2];

    // ---------------- Phase A ----------------
#pragma unroll
    for (int i = 0; i < 2; ++i) {
        const int tloc = (wave * 2 + i) * 16 + p;
        const int ptg  = b * NN + point0 + tloc;
        const float x0 = x[ptg * 3 + 0], x1 = x[ptg * 3 + 1], x2 = x[ptg * 3 + 2];

        float  ev[2][8];
        bf16x8 eb[2];
#pragma unroll
        for (int s = 0; s < 2; ++s)
#pragma unroll
            for (int jj = 0; jj < 8; ++jj) {
                const int k = 32 * s + 8 * g + jj;
                float e = b_emb[k] + x0 * W_emb[k] + x1 * W_emb[H + k] + x2 * W_emb[2 * H + k];
                ev[s][jj] = e;
                eb[s][jj] = f2bf(e);
            }

        // pf matvec, bias folded into C-init
        f32x4 macc[4];
#pragma unroll
        for (int t = 0; t < 4; ++t) {
            const float4 bp = *(const float4*)&b_pf[16 * t + 4 * g];
            f32x4 m; m[0] = bp.x; m[1] = bp.y; m[2] = bp.z; m[3] = bp.w;
            m = MFMA32(wpfr[t][0], eb[0], m);
            m = MFMA32(wpfr[t][1], eb[1], m);
            macc[t] = m;
        }
#pragma unroll
        for (int t = 0; t < 4; ++t) {
            short4 w;
            w.x = f2bf(swish_f(macc[t][0]));
            w.y = f2bf(swish_f(macc[t][1]));
            w.z = f2bf(swish_f(macc[t][2]));
            w.w = f2bf(swish_f(macc[t][3]));
            *(short4*)&hlds[tloc * 72 + 16 * t + 4 * g] = w;
        }
        bf16x8 pfb[2];
#pragma unroll
        for (int s = 0; s < 2; ++s)
            pfb[s] = *(bf16x8*)&hlds[tloc * 72 + 32 * s + 8 * g];

        // affinity: C[obj=4g+r][point=p]
        f32x4 aacc = {0.f, 0.f, 0.f, 0.f};
#pragma unroll
        for (int s = 0; s < 2; ++s)
            aacc = MFMA32(objr[s], pfb[s], aacc);

        // softmax over 16 objects (reduce across g)
        const float mx = red_max64(fmaxf(fmaxf(aacc[0], aacc[1]), fmaxf(aacc[2], aacc[3])));
        float swv[4], ssl = 0.f;
#pragma unroll
        for (int r = 0; r < 4; ++r) { swv[r] = __expf(aacc[r] - mx); ssl += swv[r]; }
        const float inv = __builtin_amdgcn_rcpf(red_add64(ssl));

        // softmax C-layout (obj=4g+r) IS the 16x16x16 B-frag layout (k=4g+jj)
        bf16x4 sf;
#pragma unroll
        for (int r = 0; r < 4; ++r) sf[r] = f2bf(swv[r] * inv);
        swfrag[i] = sf;

        // h0 = swish(x_embed) in B-frag positions
#pragma unroll
        for (int s = 0; s < 2; ++s) {
            bf16x8 hb;
#pragma unroll
            for (int jj = 0; jj < 8; ++jj) hb[jj] = f2bf(swish_f(ev[s][jj]));
            *(bf16x8*)&hlds[tloc * 72 + 32 * s + 8 * g] = hb;
        }
    }

    // ---------------- AdaLN layers (no barriers) ----------------
    for (int l = 0; l < L; ++l) {
        bf16x8 whr[4][2];
        bf16x4 tabr[8];
#pragma unroll
        for (int t = 0; t < 4; ++t)
#pragma unroll
            for (int s = 0; s < 2; ++s)
                whr[t][s] = *(const bf16x8*)&whfrag[((l * 8 + t * 2 + s) * 64 + lane) * 8];
#pragma unroll
        for (int u = 0; u < 8; ++u)
            tabr[u] = *(const bf16x4*)&tabfrag[(((b * 6 + l) * 8 + u) * 64 + lane) * 4];

#pragma unroll
        for (int i = 0; i < 2; ++i) {
            const int tloc = (wave * 2 + i) * 16 + p;
            const bf16x8 hb0 = *(bf16x8*)&hlds[tloc * 72 + 8 * g];
            const bf16x8 hb1 = *(bf16x8*)&hlds[tloc * 72 + 32 + 8 * g];
            const bf16x4 sf  = swfrag[i];

            // scale part of sel-mix (u=0..3)
            f32x4 sca[4];
#pragma unroll
            for (int u = 0; u < 4; ++u) {
                f32x4 z = {0.f, 0.f, 0.f, 0.f};
                sca[u] = MFMA16(tabr[u], sf, z);
            }

            // matvec, bias folded into C-init
            f32x4 macc[4];
#pragma unroll
            for (int t = 0; t < 4; ++t) {
                const float4 bh = *(const float4*)&b_h[l * H + 16 * t + 4 * g];
                f32x4 m; m[0] = bh.x; m[1] = bh.y; m[2] = bh.z; m[3] = bh.w;
                m = MFMA32(whr[t][0], hb0, m);
                m = MFMA32(whr[t][1], hb1, m);
                macc[t] = m;
            }

            float hn[4][4], s1 = 0.f, s2 = 0.f;
#pragma unroll
            for (int t = 0; t < 4; ++t)
#pragma unroll
                for (int r = 0; r < 4; ++r) {
                    const float v = swish_f(macc[t][r]);
                    hn[t][r] = v; s1 += v; s2 += v * v;
                }
            s1 = red_add64(s1);
            s2 = red_add64(s2);
            const float mu  = s1 * (1.0f / 64.0f);
            const float var = s2 * (1.0f / 64.0f) - mu * mu;
            const float rin = rsqrtf(var + EPSV);

            // shift part of sel-mix (u=4..7), issued just before the apply
            f32x4 sha[4];
#pragma unroll
            for (int u = 0; u < 4; ++u) {
                f32x4 z = {0.f, 0.f, 0.f, 0.f};
                sha[u] = MFMA16(tabr[4 + u], sf, z);
            }

            if (l < L - 1) {
#pragma unroll
                for (int t = 0; t < 4; ++t) {
                    const float4 gg = *(const float4*)&ln_g[l * H + 16 * t + 4 * g];
                    const float4 bb = *(const float4*)&ln_b[l * H + 16 * t + 4 * g];
                    float ggv[4]; ggv[0] = gg.x; ggv[1] = gg.y; ggv[2] = gg.z; ggv[3] = gg.w;
                    float bbv[4]; bbv[0] = bb.x; bbv[1] = bb.y; bbv[2] = bb.z; bbv[3] = bb.w;
                    short wv[4];
#pragma unroll
                    for (int r = 0; r < 4; ++r) {
                        const float lnv = (hn[t][r] - mu) * rin * ggv[r] + bbv[r];
                        wv[r] = f2bf(lnv * (1.0f + sca[t][r]) + sha[t][r]);
                    }
                    short4 w; w.x = wv[0]; w.y = wv[1]; w.z = wv[2]; w.w = wv[3];
                    *(short4*)&hlds[tloc * 72 + 16 * t + 4 * g] = w;
                }
            } else {
                float d0 = 0.f, d1 = 0.f, d2 = 0.f;
#pragma unroll
                for (int t = 0; t < 4; ++t) {
                    const float4 gg = *(const float4*)&ln_g[l * H + 16 * t + 4 * g];
                    const float4 bb = *(const float4*)&ln_b[l * H + 16 * t + 4 * g];
                    float ggv[4]; ggv[0] = gg.x; ggv[1] = gg.y; ggv[2] = gg.z; ggv[3] = gg.w;
                    float bbv[4]; bbv[0] = bb.x; bbv[1] = bb.y; bbv[2] = bb.z; bbv[3] = bb.w;
                    const float4 w0 = *(const float4*)&W_out[(16 * t + 4 * g) * 3];
                    const float4 w1 = *(const float4*)&W_out[(16 * t + 4 * g) * 3 + 4];
                    const float4 w2 = *(const float4*)&W_out[(16 * t + 4 * g) * 3 + 8];
                    float wv[12];
                    wv[0] = w0.x; wv[1] = w0.y; wv[2]  = w0.z; wv[3]  = w0.w;
                    wv[4] = w1.x; wv[5] = w1.y; wv[6]  = w1.z; wv[7]  = w1.w;
                    wv[8] = w2.x; wv[9] = w2.y; wv[10] = w2.z; wv[11] = w2.w;
#pragma unroll
                    for (int r = 0; r < 4; ++r) {
                        const float lnv = (hn[t][r] - mu) * rin * ggv[r] + bbv[r];
                        const float hv  = lnv * (1.0f + sca[t][r]) + sha[t][r];
                        d0 += hv * wv[r * 3 + 0];
                        d1 += hv * wv[r * 3 + 1];
                        d2 += hv * wv[r * 3 + 2];
                    }
                }
                d0 = red_add64(d0);
                d1 = red_add64(d1);
                d2 = red_add64(d2);
                if (g == 0) {
                    const int ptg = b * NN + point0 + tloc;
                    out[ptg * 3 + 0] = d0 + b_out[0];
                    out[ptg * 3 + 1] = d1 + b_out[1];
                    out[ptg * 3 + 2] = d2 + b_out[2];
                }
            }
        }
    }
}

extern "C" void kernel_launch(void* const* d_in, const int* in_sizes, int n_in,
                              void* d_out, int out_size, void* d_ws, size_t ws_size,
                              hipStream_t stream) {
    const float* x     = (const float*)d_in[0];
    const float* c     = (const float*)d_in[1];
    const float* t     = (const float*)d_in[2];
    const float* W_emb = (const float*)d_in[3];
    const float* b_emb = (const float*)d_in[4];
    const float* W_pf  = (const float*)d_in[5];
    const float* b_pf  = (const float*)d_in[6];
    const float* W_of  = (const float*)d_in[7];
    const float* b_of  = (const float*)d_in[8];
    const float* W_c1  = (const float*)d_in[9];
    const float* b_c1  = (const float*)d_in[10];
    const float* W_c2  = (const float*)d_in[11];
    const float* b_c2  = (const float*)d_in[12];
    const float* W_h   = (const float*)d_in[13];
    const float* b_h   = (const float*)d_in[14];
    const float* W_ss  = (const float*)d_in[15];
    const float* b_ss  = (const float*)d_in[16];
    const float* ln_g  = (const float*)d_in[17];
    const float* ln_b  = (const float*)d_in[18];
    const float* W_out = (const float*)d_in[19];
    const float* b_out = (const float*)d_in[20];
    float* out = (float*)d_out;

    short* wsb      = (short*)d_ws;
    short* objffrag = wsb + OFF_OBJF;
    short* tabfrag  = wsb + OFF_TAB;
    short* whfrag   = wsb + OFF_WH;
    short* wpffrag  = wsb + OFF_WPF;

    setup_all<<<544, 256, 0, stream>>>(c, t, W_of, b_of, W_c1, b_c1,
                                       W_c2, b_c2, W_ss, b_ss, W_h, W_pf,
                                       objffrag, tabfrag, whfrag, wpffrag);
    main_kernel<<<2048, 256, 0, stream>>>(x, W_emb, b_emb, b_pf, b_h, ln_g, ln_b,
                                          W_out, b_out, objffrag, tabfrag,
                                          whfrag, wpffrag, out);
}

// Round 12
// 104.600 us; speedup vs baseline: 1.4975x; 1.4975x over previous
//
#include <hip/hip_runtime.h>
#include <hip/hip_bf16.h>
#include <math.h>

#define H   64
#define L   6
#define TE  32
#define SEL 64
#define CD  128
#define DC  128
#define KK  16
#define BB  32
#define NN  8192
#define EPSV 1e-6f

typedef float f32x4  __attribute__((ext_vector_type(4)));
typedef short bf16x8 __attribute__((ext_vector_type(8)));
typedef short bf16x4 __attribute__((ext_vector_type(4)));

__device__ __forceinline__ float swish_f(float v) {
    return v * __builtin_amdgcn_rcpf(1.0f + __expf(-v));
}
__device__ __forceinline__ short f2bf(float f) {
    __hip_bfloat16 h = __float2bfloat16(f);
    return *reinterpret_cast<short*>(&h);
}

// Cross-lane all-reduce over lane-bits 4,5 (R9/R10-verified correct).
// R7/R8 LESSON: never hand-roll permlane in inline asm.
#if __has_builtin(__builtin_amdgcn_permlane16_swap) && __has_builtin(__builtin_amdgcn_permlane32_swap)
__device__ __forceinline__ float red_add64(float x) {
    auto r16 = __builtin_amdgcn_permlane16_swap(__float_as_uint(x), __float_as_uint(x), false, false);
    float s = __uint_as_float(r16[0]) + __uint_as_float(r16[1]);
    auto r32 = __builtin_amdgcn_permlane32_swap(__float_as_uint(s), __float_as_uint(s), false, false);
    return __uint_as_float(r32[0]) + __uint_as_float(r32[1]);
}
__device__ __forceinline__ float red_max64(float x) {
    auto r16 = __builtin_amdgcn_permlane16_swap(__float_as_uint(x), __float_as_uint(x), false, false);
    float s = fmaxf(__uint_as_float(r16[0]), __uint_as_float(r16[1]));
    auto r32 = __builtin_amdgcn_permlane32_swap(__float_as_uint(s), __float_as_uint(s), false, false);
    return fmaxf(__uint_as_float(r32[0]), __uint_as_float(r32[1]));
}
#else
__device__ __forceinline__ float red_add64(float x) {
    x += __shfl_xor(x, 16);
    x += __shfl_xor(x, 32);
    return x;
}
__device__ __forceinline__ float red_max64(float x) {
    x = fmaxf(x, __shfl_xor(x, 16));
    x = fmaxf(x, __shfl_xor(x, 32));
    return x;
}
#endif

// 16x16x16 bf16 MFMA: builtin spelling ...16x16x16bf16_1k; asm fallback with
// EARLY-CLOBBER dest so D never aliases A/B/C (R4's corruption).
#if __has_builtin(__builtin_amdgcn_mfma_f32_16x16x16bf16_1k)
#define MFMA16(a, b, c) __builtin_amdgcn_mfma_f32_16x16x16bf16_1k(a, b, c, 0, 0, 0)
#else
__device__ __forceinline__ f32x4 mfma16_asm(bf16x4 a, bf16x4 b, f32x4 c) {
    f32x4 d;
    asm("v_mfma_f32_16x16x16_bf16 %0, %1, %2, %3" : "=&v"(d) : "v"(a), "v"(b), "v"(c));
    return d;
}
#define MFMA16(a, b, c) mfma16_asm(a, b, c)
#endif
#define MFMA32(a, b, c) __builtin_amdgcn_mfma_f32_16x16x32_bf16(a, b, c, 0, 0, 0)

// ws layout (shorts):
//   objffrag [32][2][64][8]     = 32768
//   tabfrag  [32][6][8][64][4]  = 393216   (u=0..3: A=g*scale; u=4..7: B=b*scale+shift)
//   whfrag   [6][4][2][64][8]   = 24576
//   wpffrag  [4][2][64][8]      = 4096
#define OFF_OBJF 0
#define OFF_TAB  32768
#define OFF_WH   425984
#define OFF_WPF  450560

// ---------------------------------------------------------------------------
// Fused setup: blocks 0..511 per-(b,k) object tables; blocks 512..543 weight
// A-frags. Tab fold (R12): with LN fold, main computes hv = z*A + B where
//   A = MFMA(tabA, sw, C0=g),  tabA[j,k] = g[j]*scale[j,k]
//   B = MFMA(tabB, sw, C0=b),  tabB[j,k] = b[j]*scale[j,k] + shift[j,k]
// (scale/shift already include b_ss; C0 bias legal since sum_k sw = 1 is NOT
//  needed — bias rides the f32 MFMA C operand.)
// ---------------------------------------------------------------------------
__global__ void setup_all(const float* __restrict__ c, const float* __restrict__ t,
                          const float* __restrict__ W_of, const float* __restrict__ b_of,
                          const float* __restrict__ W_c1, const float* __restrict__ b_c1,
                          const float* __restrict__ W_c2, const float* __restrict__ b_c2,
                          const float* __restrict__ W_ss, const float* __restrict__ b_ss,
                          const float* __restrict__ ln_g, const float* __restrict__ ln_b,
                          const float* __restrict__ W_h,  const float* __restrict__ W_pf,
                          short* __restrict__ objffrag, short* __restrict__ tabfrag,
                          short* __restrict__ whfrag,   short* __restrict__ wpffrag) {
    if (blockIdx.x >= 512) {
        // ---- weight A-frags: A[row=16t+(lane&15)][k=32s+8*(lane>>4)+jj] ----
        const int gid = (blockIdx.x - 512) * 256 + threadIdx.x;   // 8192 threads
        for (int idx = gid; idx < 6 * 4 * 2 * 64 * 8; idx += 8192) {
            const int jj = idx & 7, lane = (idx >> 3) & 63, s = (idx >> 9) & 1,
                      tt = (idx >> 10) & 3, l = idx >> 12;
            const int g = lane >> 4, row = 16 * tt + (lane & 15), k = 32 * s + 8 * g + jj;
            whfrag[idx] = f2bf(W_h[(l * H + k) * H + row]);
        }
        for (int idx = gid; idx < 4 * 2 * 64 * 8; idx += 8192) {
            const int jj = idx & 7, lane = (idx >> 3) & 63, s = (idx >> 9) & 1, tt = idx >> 10;
            const int g = lane >> 4, row = 16 * tt + (lane & 15), k = 32 * s + 8 * g + jj;
            wpffrag[idx] = f2bf(W_pf[k * SEL + row]);
        }
        return;
    }

    // ---- per-(b,k) object setup ----
    const int bk = blockIdx.x, b = bk >> 4, k = bk & 15;
    const int tid = threadIdx.x;                        // 0..255, work on 0..127
    __shared__ float cwt[TE + DC];
    __shared__ float c1s[CD], c2s[CD];
    __shared__ float tabraw[2 * H];

    if (tid < 16) {
        float f   = __expf(-logf(10000.0f) * (float)tid * (1.0f / 15.0f));
        float arg = t[b] * f;
        cwt[tid]      = sinf(arg);
        cwt[tid + 16] = cosf(arg);
    }
    if (tid < 128) cwt[TE + tid] = c[(b * KK + k) * DC + tid];
    __syncthreads();

    if (tid < SEL) {   // object_features -> A-frag rows = object k, k-dim = tid
        float a = b_of[tid];
        for (int d = 0; d < TE + DC; ++d) a += cwt[d] * W_of[d * SEL + tid];
        a = swish_f(a);
        const int s = tid >> 5, g = (tid >> 3) & 3, jj = tid & 7;
        objffrag[(((b * 2 + s) * 64) + (16 * g + k)) * 8 + jj] = f2bf(a);
    }
    if (tid < 128) {
        float a = b_c1[tid];
        for (int d = 0; d < TE + DC; ++d) a += cwt[d] * W_c1[d * CD + tid];
        c1s[tid] = swish_f(a);
    }
    __syncthreads();
    if (tid < 128) {
        float a = b_c2[tid];
        for (int d = 0; d < CD; ++d) a += c1s[d] * W_c2[d * CD + tid];
        c2s[tid] = swish_f(a);
    }
    __syncthreads();

    // tab rows -> folded A/B tables.
    // A-frag (16x16x16): u=j>>4 (+4 for B), row=j&15, lane=16*(k>>2)+row, jj=k&3
    for (int l = 0; l < L; ++l) {
        if (tid < 128) {
            const float* W = W_ss + l * CD * (2 * H);
            float a = b_ss[l * (2 * H) + tid];
            for (int d = 0; d < CD; ++d) a += c2s[d] * W[d * (2 * H) + tid];
            tabraw[tid] = a;
        }
        __syncthreads();
        if (tid < 128) {
            const int j = tid & 63;
            const int u = (j >> 4) + ((tid < 64) ? 0 : 4);
            const int row = j & 15, lane = 16 * (k >> 2) + row, jj = k & 3;
            float v;
            if (tid < 64) v = ln_g[l * H + j] * tabraw[j];                       // tabA
            else          v = ln_b[l * H + j] * tabraw[j] + tabraw[64 + j];      // tabB
            tabfrag[(((b * 6 + l) * 8 + u) * 64 + lane) * 4 + jj] = f2bf(v);
        }
        __syncthreads();
    }
}

// ---------------------------------------------------------------------------
// Main: 2048 blocks x 256 threads (4 waves), 2 point-tiles/wave (128 pts/
// block), ZERO barriers (hlds wave-exclusive). (256,3) is the proven no-spill
// point; (256,4) forces a 64/64 VGPR/AGPR split and spills (R3, R11) — do not
// revisit. LN-apply folded into sel-mix MFMA C-init (R12): hv = z*A + B.
// ---------------------------------------------------------------------------
__global__ __launch_bounds__(256, 3) void main_kernel(
    const float* __restrict__ x,
    const float* __restrict__ W_emb, const float* __restrict__ b_emb,
    const float* __restrict__ b_pf,  const float* __restrict__ b_h,
    const float* __restrict__ ln_g,  const float* __restrict__ ln_b,
    const float* __restrict__ W_out, const float* __restrict__ b_out,
    const short* __restrict__ objffrag, const short* __restrict__ tabfrag,
    const short* __restrict__ whfrag,   const short* __restrict__ wpffrag,
    float* __restrict__ out) {

    __shared__ short hlds[128 * 72];        // [point][dim], stride 72 shorts

    const int tid  = threadIdx.x;
    const int wave = tid >> 6, lane = tid & 63;
    const int p = lane & 15, g = lane >> 4;
    const int b = blockIdx.x >> 6;                  // 64 blocks / batch
    const int point0 = (blockIdx.x & 63) << 7;      // 128 points / block

    bf16x8 wpfr[4][2], objr[2];
#pragma unroll
    for (int t = 0; t < 4; ++t)
#pragma unroll
        for (int s = 0; s < 2; ++s)
            wpfr[t][s] = *(const bf16x8*)&wpffrag[(((t * 2 + s) * 64) + lane) * 8];
#pragma unroll
    for (int s = 0; s < 2; ++s)
        objr[s] = *(const bf16x8*)&objffrag[(((b * 2 + s) * 64) + lane) * 8];

    bf16x4 swfrag[2];

    // ---------------- Phase A ----------------
#pragma unroll
    for (int i = 0; i < 2; ++i) {
        const int tloc = (wave * 2 + i) * 16 + p;
        const int ptg  = b * NN + point0 + tloc;
        const float x0 = x[ptg * 3 + 0], x1 = x[ptg * 3 + 1], x2 = x[ptg * 3 + 2];

        float  ev[2][8];
        bf16x8 eb[2];
#pragma unroll
        for (int s = 0; s < 2; ++s)
#pragma unroll
            for (int jj = 0; jj < 8; ++jj) {
                const int k = 32 * s + 8 * g + jj;
                float e = b_emb[k] + x0 * W_emb[k] + x1 * W_emb[H + k] + x2 * W_emb[2 * H + k];
                ev[s][jj] = e;
                eb[s][jj] = f2bf(e);
            }

        // pf matvec, bias folded into C-init
        f32x4 macc[4];
#pragma unroll
        for (int t = 0; t < 4; ++t) {
            const float4 bp = *(const float4*)&b_pf[16 * t + 4 * g];
            f32x4 m; m[0] = bp.x; m[1] = bp.y; m[2] = bp.z; m[3] = bp.w;
            m = MFMA32(wpfr[t][0], eb[0], m);
            m = MFMA32(wpfr[t][1], eb[1], m);
            macc[t] = m;
        }
#pragma unroll
        for (int t = 0; t < 4; ++t) {
            short4 w;
            w.x = f2bf(swish_f(macc[t][0]));
            w.y = f2bf(swish_f(macc[t][1]));
            w.z = f2bf(swish_f(macc[t][2]));
            w.w = f2bf(swish_f(macc[t][3]));
            *(short4*)&hlds[tloc * 72 + 16 * t + 4 * g] = w;
        }
        bf16x8 pfb[2];
#pragma unroll
        for (int s = 0; s < 2; ++s)
            pfb[s] = *(bf16x8*)&hlds[tloc * 72 + 32 * s + 8 * g];

        // affinity: C[obj=4g+r][point=p]
        f32x4 aacc = {0.f, 0.f, 0.f, 0.f};
#pragma unroll
        for (int s = 0; s < 2; ++s)
            aacc = MFMA32(objr[s], pfb[s], aacc);

        // softmax over 16 objects (reduce across g)
        const float mx = red_max64(fmaxf(fmaxf(aacc[0], aacc[1]), fmaxf(aacc[2], aacc[3])));
        float swv[4], ssl = 0.f;
#pragma unroll
        for (int r = 0; r < 4; ++r) { swv[r] = __expf(aacc[r] - mx); ssl += swv[r]; }
        const float inv = __builtin_amdgcn_rcpf(red_add64(ssl));

        // softmax C-layout (obj=4g+r) IS the 16x16x16 B-frag layout (k=4g+jj)
        bf16x4 sf;
#pragma unroll
        for (int r = 0; r < 4; ++r) sf[r] = f2bf(swv[r] * inv);
        swfrag[i] = sf;

        // h0 = swish(x_embed) in B-frag positions
#pragma unroll
        for (int s = 0; s < 2; ++s) {
            bf16x8 hb;
#pragma unroll
            for (int jj = 0; jj < 8; ++jj) hb[jj] = f2bf(swish_f(ev[s][jj]));
            *(bf16x8*)&hlds[tloc * 72 + 32 * s + 8 * g] = hb;
        }
    }

    // ---------------- AdaLN layers (no barriers) ----------------
    for (int l = 0; l < L; ++l) {
        bf16x8 whr[4][2];
        bf16x4 tabr[8];
#pragma unroll
        for (int t = 0; t < 4; ++t)
#pragma unroll
            for (int s = 0; s < 2; ++s)
                whr[t][s] = *(const bf16x8*)&whfrag[((l * 8 + t * 2 + s) * 64 + lane) * 8];
#pragma unroll
        for (int u = 0; u < 8; ++u)
            tabr[u] = *(const bf16x4*)&tabfrag[(((b * 6 + l) * 8 + u) * 64 + lane) * 4];

#pragma unroll
        for (int i = 0; i < 2; ++i) {
            const int tloc = (wave * 2 + i) * 16 + p;
            const bf16x8 hb0 = *(bf16x8*)&hlds[tloc * 72 + 8 * g];
            const bf16x8 hb1 = *(bf16x8*)&hlds[tloc * 72 + 32 + 8 * g];
            const bf16x4 sf  = swfrag[i];

            // A = g + g*sca  (C-init = ln_g row)
            f32x4 sca[4];
#pragma unroll
            for (int u = 0; u < 4; ++u) {
                const float4 gg = *(const float4*)&ln_g[l * H + 16 * u + 4 * g];
                f32x4 z; z[0] = gg.x; z[1] = gg.y; z[2] = gg.z; z[3] = gg.w;
                sca[u] = MFMA16(tabr[u], sf, z);
            }

            // matvec, bias folded into C-init
            f32x4 macc[4];
#pragma unroll
            for (int t = 0; t < 4; ++t) {
                const float4 bh = *(const float4*)&b_h[l * H + 16 * t + 4 * g];
                f32x4 m; m[0] = bh.x; m[1] = bh.y; m[2] = bh.z; m[3] = bh.w;
                m = MFMA32(whr[t][0], hb0, m);
                m = MFMA32(whr[t][1], hb1, m);
                macc[t] = m;
            }

            float hn[4][4], s1 = 0.f, s2 = 0.f;
#pragma unroll
            for (int t = 0; t < 4; ++t)
#pragma unroll
                for (int r = 0; r < 4; ++r) {
                    const float v = swish_f(macc[t][r]);
                    hn[t][r] = v; s1 += v; s2 += v * v;
                }
            s1 = red_add64(s1);
            s2 = red_add64(s2);
            const float mu  = s1 * (1.0f / 64.0f);
            const float var = s2 * (1.0f / 64.0f) - mu * mu;
            const float rin = rsqrtf(var + EPSV);

            // B = b + b*sca + sha  (C-init = ln_b row), issued after stats
            f32x4 sha[4];
#pragma unroll
            for (int u = 0; u < 4; ++u) {
                const float4 bb = *(const float4*)&ln_b[l * H + 16 * u + 4 * g];
                f32x4 z; z[0] = bb.x; z[1] = bb.y; z[2] = bb.z; z[3] = bb.w;
                sha[u] = MFMA16(tabr[4 + u], sf, z);
            }

            if (l < L - 1) {
#pragma unroll
                for (int t = 0; t < 4; ++t) {
                    short wv[4];
#pragma unroll
                    for (int r = 0; r < 4; ++r) {
                        const float z = (hn[t][r] - mu) * rin;
                        wv[r] = f2bf(fmaf(z, sca[t][r], sha[t][r]));
                    }
                    short4 w; w.x = wv[0]; w.y = wv[1]; w.z = wv[2]; w.w = wv[3];
                    *(short4*)&hlds[tloc * 72 + 16 * t + 4 * g] = w;
                }
            } else {
                float d0 = 0.f, d1 = 0.f, d2 = 0.f;
#pragma unroll
                for (int t = 0; t < 4; ++t) {
                    const float4 w0 = *(const float4*)&W_out[(16 * t + 4 * g) * 3];
                    const float4 w1 = *(const float4*)&W_out[(16 * t + 4 * g) * 3 + 4];
                    const float4 w2 = *(const float4*)&W_out[(16 * t + 4 * g) * 3 + 8];
                    float wv[12];
                    wv[0] = w0.x; wv[1] = w0.y; wv[2]  = w0.z; wv[3]  = w0.w;
                    wv[4] = w1.x; wv[5] = w1.y; wv[6]  = w1.z; wv[7]  = w1.w;
                    wv[8] = w2.x; wv[9] = w2.y; wv[10] = w2.z; wv[11] = w2.w;
#pragma unroll
                    for (int r = 0; r < 4; ++r) {
                        const float z  = (hn[t][r] - mu) * rin;
                        const float hv = fmaf(z, sca[t][r], sha[t][r]);
                        d0 += hv * wv[r * 3 + 0];
                        d1 += hv * wv[r * 3 + 1];
                        d2 += hv * wv[r * 3 + 2];
                    }
                }
                d0 = red_add64(d0);
                d1 = red_add64(d1);
                d2 = red_add64(d2);
                if (g == 0) {
                    const int ptg = b * NN + point0 + tloc;
                    out[ptg * 3 + 0] = d0 + b_out[0];
                    out[ptg * 3 + 1] = d1 + b_out[1];
                    out[ptg * 3 + 2] = d2 + b_out[2];
                }
            }
        }
    }
}

extern "C" void kernel_launch(void* const* d_in, const int* in_sizes, int n_in,
                              void* d_out, int out_size, void* d_ws, size_t ws_size,
                              hipStream_t stream) {
    const float* x     = (const float*)d_in[0];
    const float* c     = (const float*)d_in[1];
    const float* t     = (const float*)d_in[2];
    const float* W_emb = (const float*)d_in[3];
    const float* b_emb = (const float*)d_in[4];
    const float* W_pf  = (const float*)d_in[5];
    const float* b_pf  = (const float*)d_in[6];
    const float* W_of  = (const float*)d_in[7];
    const float* b_of  = (const float*)d_in[8];
    const float* W_c1  = (const float*)d_in[9];
    const float* b_c1  = (const float*)d_in[10];
    const float* W_c2  = (const float*)d_in[11];
    const float* b_c2  = (const float*)d_in[12];
    const float* W_h   = (const float*)d_in[13];
    const float* b_h   = (const float*)d_in[14];
    const float* W_ss  = (const float*)d_in[15];
    const float* b_ss  = (const float*)d_in[16];
    const float* ln_g  = (const float*)d_in[17];
    const float* ln_b  = (const float*)d_in[18];
    const float* W_out = (const float*)d_in[19];
    const float* b_out = (const float*)d_in[20];
    float* out = (float*)d_out;

    short* wsb      = (short*)d_ws;
    short* objffrag = wsb + OFF_OBJF;
    short* tabfrag  = wsb + OFF_TAB;
    short* whfrag   = wsb + OFF_WH;
    short* wpffrag  = wsb + OFF_WPF;

    setup_all<<<544, 256, 0, stream>>>(c, t, W_of, b_of, W_c1, b_c1,
                                       W_c2, b_c2, W_ss, b_ss, ln_g, ln_b,
                                       W_h, W_pf,
                                       objffrag, tabfrag, whfrag, wpffrag);
    main_kernel<<<2048, 256, 0, stream>>>(x, W_emb, b_emb, b_pf, b_h, ln_g, ln_b,
                                          W_out, b_out, objffrag, tabfrag,
                                          whfrag, wpffrag, out);
}

// Round 14
// 104.183 us; speedup vs baseline: 1.5035x; 1.0040x over previous
//
#include <hip/hip_runtime.h>
#include <hip/hip_bf16.h>
#include <math.h>

#define H   64
#define L   6
#define TE  32
#define SEL 64
#define CD  128
#define DC  128
#define KK  16
#define BB  32
#define NN  8192
#define EPSV 1e-6f

typedef float f32x4  __attribute__((ext_vector_type(4)));
typedef short bf16x8 __attribute__((ext_vector_type(8)));
typedef short bf16x4 __attribute__((ext_vector_type(4)));

__device__ __forceinline__ float swish_f(float v) {
    return v * __builtin_amdgcn_rcpf(1.0f + __expf(-v));
}
__device__ __forceinline__ short f2bf(float f) {
    __hip_bfloat16 h = __float2bfloat16(f);
    return *reinterpret_cast<short*>(&h);
}

// 4-way ILP dot product (R13 intent, R14 fixed as a template — the macro
// token-pasting version didn't expand function-like macros). Without
// -ffast-math the compiler cannot re-associate a serial `a += ...` chain;
// 4 accumulators cut the dependent-FMA chain 4x in the setup blocks.
template <typename F>
__device__ __forceinline__ float dot4(int n, F f) {
    float a0 = 0.f, a1 = 0.f, a2 = 0.f, a3 = 0.f;
    for (int d = 0; d < n; d += 4) {
        a0 = fmaf(f(d).x,     f(d).y,     a0);
        a1 = fmaf(f(d + 1).x, f(d + 1).y, a1);
        a2 = fmaf(f(d + 2).x, f(d + 2).y, a2);
        a3 = fmaf(f(d + 3).x, f(d + 3).y, a3);
    }
    return (a0 + a1) + (a2 + a3);
}

// Cross-lane all-reduce over lane-bits 4,5 (R9/R10-verified correct).
// R7/R8 LESSON: never hand-roll permlane in inline asm.
#if __has_builtin(__builtin_amdgcn_permlane16_swap) && __has_builtin(__builtin_amdgcn_permlane32_swap)
__device__ __forceinline__ float red_add64(float x) {
    auto r16 = __builtin_amdgcn_permlane16_swap(__float_as_uint(x), __float_as_uint(x), false, false);
    float s = __uint_as_float(r16[0]) + __uint_as_float(r16[1]);
    auto r32 = __builtin_amdgcn_permlane32_swap(__float_as_uint(s), __float_as_uint(s), false, false);
    return __uint_as_float(r32[0]) + __uint_as_float(r32[1]);
}
__device__ __forceinline__ float red_max64(float x) {
    auto r16 = __builtin_amdgcn_permlane16_swap(__float_as_uint(x), __float_as_uint(x), false, false);
    float s = fmaxf(__uint_as_float(r16[0]), __uint_as_float(r16[1]));
    auto r32 = __builtin_amdgcn_permlane32_swap(__float_as_uint(s), __float_as_uint(s), false, false);
    return fmaxf(__uint_as_float(r32[0]), __uint_as_float(r32[1]));
}
#else
__device__ __forceinline__ float red_add64(float x) {
    x += __shfl_xor(x, 16);
    x += __shfl_xor(x, 32);
    return x;
}
__device__ __forceinline__ float red_max64(float x) {
    x = fmaxf(x, __shfl_xor(x, 16));
    x = fmaxf(x, __shfl_xor(x, 32));
    return x;
}
#endif

// 16x16x16 bf16 MFMA: builtin spelling ...16x16x16bf16_1k; asm fallback with
// EARLY-CLOBBER dest so D never aliases A/B/C (R4's corruption).
#if __has_builtin(__builtin_amdgcn_mfma_f32_16x16x16bf16_1k)
#define MFMA16(a, b, c) __builtin_amdgcn_mfma_f32_16x16x16bf16_1k(a, b, c, 0, 0, 0)
#else
__device__ __forceinline__ f32x4 mfma16_asm(bf16x4 a, bf16x4 b, f32x4 c) {
    f32x4 d;
    asm("v_mfma_f32_16x16x16_bf16 %0, %1, %2, %3" : "=&v"(d) : "v"(a), "v"(b), "v"(c));
    return d;
}
#define MFMA16(a, b, c) mfma16_asm(a, b, c)
#endif
#define MFMA32(a, b, c) __builtin_amdgcn_mfma_f32_16x16x32_bf16(a, b, c, 0, 0, 0)

// ws layout (shorts):
//   objffrag [32][2][64][8]     = 32768
//   tabfrag  [32][6][8][64][4]  = 393216   (u=0..3: A=g*scale; u=4..7: B=b*scale+shift)
//   whfrag   [6][4][2][64][8]   = 24576
//   wpffrag  [4][2][64][8]      = 4096
#define OFF_OBJF 0
#define OFF_TAB  32768
#define OFF_WH   425984
#define OFF_WPF  450560

// ---------------------------------------------------------------------------
// Fused setup: blocks 0..511 per-(b,k) object tables; blocks 512..543 weight
// A-frags. Tab fold (R12): main computes hv = z*A + B where
//   A = MFMA(tabA, sw, C0=g),  tabA[j,k] = g[j]*scale[j,k]
//   B = MFMA(tabB, sw, C0=b),  tabB[j,k] = b[j]*scale[j,k] + shift[j,k]
// ---------------------------------------------------------------------------
__global__ void setup_all(const float* __restrict__ c, const float* __restrict__ t,
                          const float* __restrict__ W_of, const float* __restrict__ b_of,
                          const float* __restrict__ W_c1, const float* __restrict__ b_c1,
                          const float* __restrict__ W_c2, const float* __restrict__ b_c2,
                          const float* __restrict__ W_ss, const float* __restrict__ b_ss,
                          const float* __restrict__ ln_g, const float* __restrict__ ln_b,
                          const float* __restrict__ W_h,  const float* __restrict__ W_pf,
                          short* __restrict__ objffrag, short* __restrict__ tabfrag,
                          short* __restrict__ whfrag,   short* __restrict__ wpffrag) {
    if (blockIdx.x >= 512) {
        // ---- weight A-frags: A[row=16t+(lane&15)][k=32s+8*(lane>>4)+jj] ----
        const int gid = (blockIdx.x - 512) * 256 + threadIdx.x;   // 8192 threads
        for (int idx = gid; idx < 6 * 4 * 2 * 64 * 8; idx += 8192) {
            const int jj = idx & 7, lane = (idx >> 3) & 63, s = (idx >> 9) & 1,
                      tt = (idx >> 10) & 3, l = idx >> 12;
            const int g = lane >> 4, row = 16 * tt + (lane & 15), k = 32 * s + 8 * g + jj;
            whfrag[idx] = f2bf(W_h[(l * H + k) * H + row]);
        }
        for (int idx = gid; idx < 4 * 2 * 64 * 8; idx += 8192) {
            const int jj = idx & 7, lane = (idx >> 3) & 63, s = (idx >> 9) & 1, tt = idx >> 10;
            const int g = lane >> 4, row = 16 * tt + (lane & 15), k = 32 * s + 8 * g + jj;
            wpffrag[idx] = f2bf(W_pf[k * SEL + row]);
        }
        return;
    }

    // ---- per-(b,k) object setup ----
    const int bk = blockIdx.x, b = bk >> 4, k = bk & 15;
    const int tid = threadIdx.x;                        // 0..255, work on 0..127
    __shared__ float cwt[TE + DC];
    __shared__ float c1s[CD], c2s[CD];
    __shared__ float tabraw[2 * H];

    if (tid < 16) {
        float f   = __expf(-logf(10000.0f) * (float)tid * (1.0f / 15.0f));
        float arg = t[b] * f;
        cwt[tid]      = sinf(arg);
        cwt[tid + 16] = cosf(arg);
    }
    if (tid < 128) cwt[TE + tid] = c[(b * KK + k) * DC + tid];
    __syncthreads();

    if (tid < SEL) {   // object_features -> A-frag rows = object k, k-dim = tid
        const float acc = dot4(TE + DC, [&](int d) {
            return float2{cwt[d], W_of[d * SEL + tid]};
        });
        float a = swish_f(b_of[tid] + acc);
        const int s = tid >> 5, g = (tid >> 3) & 3, jj = tid & 7;
        objffrag[(((b * 2 + s) * 64) + (16 * g + k)) * 8 + jj] = f2bf(a);
    }
    if (tid < 128) {
        const float acc = dot4(TE + DC, [&](int d) {
            return float2{cwt[d], W_c1[d * CD + tid]};
        });
        c1s[tid] = swish_f(b_c1[tid] + acc);
    }
    __syncthreads();
    if (tid < 128) {
        const float acc = dot4(CD, [&](int d) {
            return float2{c1s[d], W_c2[d * CD + tid]};
        });
        c2s[tid] = swish_f(b_c2[tid] + acc);
    }
    __syncthreads();

    // tab rows -> folded A/B tables.
    // A-frag (16x16x16): u=j>>4 (+4 for B), row=j&15, lane=16*(k>>2)+row, jj=k&3
    for (int l = 0; l < L; ++l) {
        if (tid < 128) {
            const float* W = W_ss + l * CD * (2 * H);
            const float acc = dot4(CD, [&](int d) {
                return float2{c2s[d], W[d * (2 * H) + tid]};
            });
            tabraw[tid] = b_ss[l * (2 * H) + tid] + acc;
        }
        __syncthreads();
        if (tid < 128) {
            const int j = tid & 63;
            const int u = (j >> 4) + ((tid < 64) ? 0 : 4);
            const int row = j & 15, lane = 16 * (k >> 2) + row, jj = k & 3;
            float v;
            if (tid < 64) v = ln_g[l * H + j] * tabraw[j];                       // tabA
            else          v = ln_b[l * H + j] * tabraw[j] + tabraw[64 + j];      // tabB
            tabfrag[(((b * 6 + l) * 8 + u) * 64 + lane) * 4 + jj] = f2bf(v);
        }
        __syncthreads();
    }
}

// ---------------------------------------------------------------------------
// Main (UNCHANGED from R12 — proven 97.5us steady, FETCH 5.2MB, no spills):
// 2048 blocks x 256 threads (4 waves), 2 point-tiles/wave, ZERO barriers.
// (256,3) is the no-spill point; (256,4) forces 64/64 VGPR/AGPR split and
// spills (R3, R11) — do not revisit. LN-apply folded into sel-mix MFMA C-init.
// ---------------------------------------------------------------------------
__global__ __launch_bounds__(256, 3) void main_kernel(
    const float* __restrict__ x,
    const float* __restrict__ W_emb, const float* __restrict__ b_emb,
    const float* __restrict__ b_pf,  const float* __restrict__ b_h,
    const float* __restrict__ ln_g,  const float* __restrict__ ln_b,
    const float* __restrict__ W_out, const float* __restrict__ b_out,
    const short* __restrict__ objffrag, const short* __restrict__ tabfrag,
    const short* __restrict__ whfrag,   const short* __restrict__ wpffrag,
    float* __restrict__ out) {

    __shared__ short hlds[128 * 72];        // [point][dim], stride 72 shorts

    const int tid  = threadIdx.x;
    const int wave = tid >> 6, lane = tid & 63;
    const int p = lane & 15, g = lane >> 4;
    const int b = blockIdx.x >> 6;                  // 64 blocks / batch
    const int point0 = (blockIdx.x & 63) << 7;      // 128 points / block

    bf16x8 wpfr[4][2], objr[2];
#pragma unroll
    for (int t = 0; t < 4; ++t)
#pragma unroll
        for (int s = 0; s < 2; ++s)
            wpfr[t][s] = *(const bf16x8*)&wpffrag[(((t * 2 + s) * 64) + lane) * 8];
#pragma unroll
    for (int s = 0; s < 2; ++s)
        objr[s] = *(const bf16x8*)&objffrag[(((b * 2 + s) * 64) + lane) * 8];

    bf16x4 swfrag[2];

    // ---------------- Phase A ----------------
#pragma unroll
    for (int i = 0; i < 2; ++i) {
        const int tloc = (wave * 2 + i) * 16 + p;
        const int ptg  = b * NN + point0 + tloc;
        const float x0 = x[ptg * 3 + 0], x1 = x[ptg * 3 + 1], x2 = x[ptg * 3 + 2];

        float  ev[2][8];
        bf16x8 eb[2];
#pragma unroll
        for (int s = 0; s < 2; ++s)
#pragma unroll
            for (int jj = 0; jj < 8; ++jj) {
                const int k = 32 * s + 8 * g + jj;
                float e = b_emb[k] + x0 * W_emb[k] + x1 * W_emb[H + k] + x2 * W_emb[2 * H + k];
                ev[s][jj] = e;
                eb[s][jj] = f2bf(e);
            }

        // pf matvec, bias folded into C-init
        f32x4 macc[4];
#pragma unroll
        for (int t = 0; t < 4; ++t) {
            const float4 bp = *(const float4*)&b_pf[16 * t + 4 * g];
            f32x4 m; m[0] = bp.x; m[1] = bp.y; m[2] = bp.z; m[3] = bp.w;
            m = MFMA32(wpfr[t][0], eb[0], m);
            m = MFMA32(wpfr[t][1], eb[1], m);
            macc[t] = m;
        }
#pragma unroll
        for (int t = 0; t < 4; ++t) {
            short4 w;
            w.x = f2bf(swish_f(macc[t][0]));
            w.y = f2bf(swish_f(macc[t][1]));
            w.z = f2bf(swish_f(macc[t][2]));
            w.w = f2bf(swish_f(macc[t][3]));
            *(short4*)&hlds[tloc * 72 + 16 * t + 4 * g] = w;
        }
        bf16x8 pfb[2];
#pragma unroll
        for (int s = 0; s < 2; ++s)
            pfb[s] = *(bf16x8*)&hlds[tloc * 72 + 32 * s + 8 * g];

        // affinity: C[obj=4g+r][point=p]
        f32x4 aacc = {0.f, 0.f, 0.f, 0.f};
#pragma unroll
        for (int s = 0; s < 2; ++s)
            aacc = MFMA32(objr[s], pfb[s], aacc);

        // softmax over 16 objects (reduce across g)
        const float mx = red_max64(fmaxf(fmaxf(aacc[0], aacc[1]), fmaxf(aacc[2], aacc[3])));
        float swv[4], ssl = 0.f;
#pragma unroll
        for (int r = 0; r < 4; ++r) { swv[r] = __expf(aacc[r] - mx); ssl += swv[r]; }
        const float inv = __builtin_amdgcn_rcpf(red_add64(ssl));

        // softmax C-layout (obj=4g+r) IS the 16x16x16 B-frag layout (k=4g+jj)
        bf16x4 sf;
#pragma unroll
        for (int r = 0; r < 4; ++r) sf[r] = f2bf(swv[r] * inv);
        swfrag[i] = sf;

        // h0 = swish(x_embed) in B-frag positions
#pragma unroll
        for (int s = 0; s < 2; ++s) {
            bf16x8 hb;
#pragma unroll
            for (int jj = 0; jj < 8; ++jj) hb[jj] = f2bf(swish_f(ev[s][jj]));
            *(bf16x8*)&hlds[tloc * 72 + 32 * s + 8 * g] = hb;
        }
    }

    // ---------------- AdaLN layers (no barriers) ----------------
    for (int l = 0; l < L; ++l) {
        bf16x8 whr[4][2];
        bf16x4 tabr[8];
#pragma unroll
        for (int t = 0; t < 4; ++t)
#pragma unroll
            for (int s = 0; s < 2; ++s)
                whr[t][s] = *(const bf16x8*)&whfrag[((l * 8 + t * 2 + s) * 64 + lane) * 8];
#pragma unroll
        for (int u = 0; u < 8; ++u)
            tabr[u] = *(const bf16x4*)&tabfrag[(((b * 6 + l) * 8 + u) * 64 + lane) * 4];

#pragma unroll
        for (int i = 0; i < 2; ++i) {
            const int tloc = (wave * 2 + i) * 16 + p;
            const bf16x8 hb0 = *(bf16x8*)&hlds[tloc * 72 + 8 * g];
            const bf16x8 hb1 = *(bf16x8*)&hlds[tloc * 72 + 32 + 8 * g];
            const bf16x4 sf  = swfrag[i];

            // A = g + g*sca  (C-init = ln_g row)
            f32x4 sca[4];
#pragma unroll
            for (int u = 0; u < 4; ++u) {
                const float4 gg = *(const float4*)&ln_g[l * H + 16 * u + 4 * g];
                f32x4 z; z[0] = gg.x; z[1] = gg.y; z[2] = gg.z; z[3] = gg.w;
                sca[u] = MFMA16(tabr[u], sf, z);
            }

            // matvec, bias folded into C-init
            f32x4 macc[4];
#pragma unroll
            for (int t = 0; t < 4; ++t) {
                const float4 bh = *(const float4*)&b_h[l * H + 16 * t + 4 * g];
                f32x4 m; m[0] = bh.x; m[1] = bh.y; m[2] = bh.z; m[3] = bh.w;
                m = MFMA32(whr[t][0], hb0, m);
                m = MFMA32(whr[t][1], hb1, m);
                macc[t] = m;
            }

            float hn[4][4], s1 = 0.f, s2 = 0.f;
#pragma unroll
            for (int t = 0; t < 4; ++t)
#pragma unroll
                for (int r = 0; r < 4; ++r) {
                    const float v = swish_f(macc[t][r]);
                    hn[t][r] = v; s1 += v; s2 += v * v;
                }
            s1 = red_add64(s1);
            s2 = red_add64(s2);
            const float mu  = s1 * (1.0f / 64.0f);
            const float var = s2 * (1.0f / 64.0f) - mu * mu;
            const float rin = rsqrtf(var + EPSV);

            // B = b + b*sca + sha  (C-init = ln_b row), issued after stats
            f32x4 sha[4];
#pragma unroll
            for (int u = 0; u < 4; ++u) {
                const float4 bb = *(const float4*)&ln_b[l * H + 16 * u + 4 * g];
                f32x4 z; z[0] = bb.x; z[1] = bb.y; z[2] = bb.z; z[3] = bb.w;
                sha[u] = MFMA16(tabr[4 + u], sf, z);
            }

            if (l < L - 1) {
#pragma unroll
                for (int t = 0; t < 4; ++t) {
                    short wv[4];
#pragma unroll
                    for (int r = 0; r < 4; ++r) {
                        const float z = (hn[t][r] - mu) * rin;
                        wv[r] = f2bf(fmaf(z, sca[t][r], sha[t][r]));
                    }
                    short4 w; w.x = wv[0]; w.y = wv[1]; w.z = wv[2]; w.w = wv[3];
                    *(short4*)&hlds[tloc * 72 + 16 * t + 4 * g] = w;
                }
            } else {
                float d0 = 0.f, d1 = 0.f, d2 = 0.f;
#pragma unroll
                for (int t = 0; t < 4; ++t) {
                    const float4 w0 = *(const float4*)&W_out[(16 * t + 4 * g) * 3];
                    const float4 w1 = *(const float4*)&W_out[(16 * t + 4 * g) * 3 + 4];
                    const float4 w2 = *(const float4*)&W_out[(16 * t + 4 * g) * 3 + 8];
                    float wv[12];
                    wv[0] = w0.x; wv[1] = w0.y; wv[2]  = w0.z; wv[3]  = w0.w;
                    wv[4] = w1.x; wv[5] = w1.y; wv[6]  = w1.z; wv[7]  = w1.w;
                    wv[8] = w2.x; wv[9] = w2.y; wv[10] = w2.z; wv[11] = w2.w;
#pragma unroll
                    for (int r = 0; r < 4; ++r) {
                        const float z  = (hn[t][r] - mu) * rin;
                        const float hv = fmaf(z, sca[t][r], sha[t][r]);
                        d0 += hv * wv[r * 3 + 0];
                        d1 += hv * wv[r * 3 + 1];
                        d2 += hv * wv[r * 3 + 2];
                    }
                }
                d0 = red_add64(d0);
                d1 = red_add64(d1);
                d2 = red_add64(d2);
                if (g == 0) {
                    const int ptg = b * NN + point0 + tloc;
                    out[ptg * 3 + 0] = d0 + b_out[0];
                    out[ptg * 3 + 1] = d1 + b_out[1];
                    out[ptg * 3 + 2] = d2 + b_out[2];
                }
            }
        }
    }
}

extern "C" void kernel_launch(void* const* d_in, const int* in_sizes, int n_in,
                              void* d_out, int out_size, void* d_ws, size_t ws_size,
                              hipStream_t stream) {
    const float* x     = (const float*)d_in[0];
    const float* c     = (const float*)d_in[1];
    const float* t     = (const float*)d_in[2];
    const float* W_emb = (const float*)d_in[3];
    const float* b_emb = (const float*)d_in[4];
    const float* W_pf  = (const float*)d_in[5];
    const float* b_pf  = (const float*)d_in[6];
    const float* W_of  = (const float*)d_in[7];
    const float* b_of  = (const float*)d_in[8];
    const float* W_c1  = (const float*)d_in[9];
    const float* b_c1  = (const float*)d_in[10];
    const float* W_c2  = (const float*)d_in[11];
    const float* b_c2  = (const float*)d_in[12];
    const float* W_h   = (const float*)d_in[13];
    const float* b_h   = (const float*)d_in[14];
    const float* W_ss  = (const float*)d_in[15];
    const float* b_ss  = (const float*)d_in[16];
    const float* ln_g  = (const float*)d_in[17];
    const float* ln_b  = (const float*)d_in[18];
    const float* W_out = (const float*)d_in[19];
    const float* b_out = (const float*)d_in[20];
    float* out = (float*)d_out;

    short* wsb      = (short*)d_ws;
    short* objffrag = wsb + OFF_OBJF;
    short* tabfrag  = wsb + OFF_TAB;
    short* whfrag   = wsb + OFF_WH;
    short* wpffrag  = wsb + OFF_WPF;

    setup_all<<<544, 256, 0, stream>>>(c, t, W_of, b_of, W_c1, b_c1,
                                       W_c2, b_c2, W_ss, b_ss, ln_g, ln_b,
                                       W_h, W_pf,
                                       objffrag, tabfrag, whfrag, wpffrag);
    main_kernel<<<2048, 256, 0, stream>>>(x, W_emb, b_emb, b_pf, b_h, ln_g, ln_b,
                                          W_out, b_out, objffrag, tabfrag,
                                          whfrag, wpffrag, out);
}